// Round 16
// baseline (441.567 us; speedup 1.0000x reference)
//
#include <hip/hip_runtime.h>

#define N_NODES 50000
#define NE0 500000
#define NE1 300000
#define NE (NE0 + NE1)
#define DD 64
#define ILV 5  // every 5th block in giant_k is a degree-count block (MLP blocks now 2x work)

typedef __bf16 bf16x8 __attribute__((ext_vector_type(8)));
typedef float f32x4 __attribute__((ext_vector_type(4)));
typedef unsigned short u16x8 __attribute__((ext_vector_type(8)));

__device__ __forceinline__ ushort f2bf(float x) {  // RNE via native cvt
  union { __bf16 h; ushort u; } v;
  v.h = (__bf16)x;
  return v.u;
}
__device__ __forceinline__ float bf2f(ushort u) {
  union { unsigned u; float f; } v;
  v.u = ((unsigned)u) << 16;
  return v.f;
}

// ==================== weight pack (B-frag order) ===========================
__global__ void pack_k(const float* __restrict__ w00, const float* __restrict__ w01,
                       const float* __restrict__ w02, const float* __restrict__ w10,
                       const float* __restrict__ w11, const float* __restrict__ w12,
                       const float* __restrict__ w20, const float* __restrict__ w21,
                       const float* __restrict__ w22, ushort* __restrict__ pk) {
  int f = blockIdx.x, l = threadIdx.x;  // 60 blocks x 64 threads
  int t = f / 20, fl = f % 20;
  int layer, nt, ks;
  if (fl < 4) { layer = 0; nt = fl; ks = 0; }
  else if (fl < 12) { layer = 1; nt = (fl - 4) >> 1; ks = (fl - 4) & 1; }
  else { layer = 2; nt = (fl - 12) >> 1; ks = (fl - 12) & 1; }
  const float* Wt[3][3] = {{w00, w01, w02}, {w10, w11, w12}, {w20, w21, w22}};
  const int K0[3] = {16, 8, 32};
  const float* W = Wt[t][layer];
  int K = (layer == 0) ? K0[t] : 64;
  int g = l >> 4, c = l & 15;
  ushort o[8];
#pragma unroll
  for (int e = 0; e < 8; ++e) {
    int k = ks * 32 + g * 8 + e, n = nt * 16 + c;
    o[e] = f2bf((k < K) ? W[k * DD + n] : 0.f);
  }
  ushort4* d4 = (ushort4*)&pk[(size_t)f * 512 + l * 8];
  d4[0] = make_ushort4(o[0], o[1], o[2], o[3]);
  d4[1] = make_ushort4(o[4], o[5], o[6], o[7]);
}

// ==================== order-free single-pass scan ==========================
__device__ __forceinline__ int block_scan_excl(int x, int tid, int* total) {
  int lane = tid & 63, w = tid >> 6;
  int incl = x;
#pragma unroll
  for (int d = 1; d < 64; d <<= 1) {
    int y = __shfl_up(incl, d);
    if (lane >= d) incl += y;
  }
  __shared__ int wsum[4];
  if (lane == 63) wsum[w] = incl;
  __syncthreads();
  int woff = 0;
  if (w > 0) woff = wsum[0];
  if (w > 1) woff += wsum[1];
  if (w > 2) woff += wsum[2];
  *total = wsum[0] + wsum[1] + wsum[2] + wsum[3];
  return woff + incl - x;
}

__global__ __launch_bounds__(256) void scan_k(const int* __restrict__ cnt,
                                              int* __restrict__ rowptr,
                                              int* __restrict__ gbase) {
  int i = blockIdx.x * 256 + threadIdx.x;
  int x = (i < N_NODES) ? cnt[i] : 0;
  int tot;
  int ex = block_scan_excl(x, threadIdx.x, &tot);
  __shared__ int base;
  if (threadIdx.x == 0) base = atomicAdd(gbase, tot);
  __syncthreads();
  if (i < N_NODES) rowptr[i] = base + ex;
}

// scatter: atomic-free. slot = rowptr[d] + rank[e]; one packed 16B store.
__global__ void scatter_k(const int* __restrict__ src, const int* __restrict__ dst,
                          const int* __restrict__ rowptr,
                          const int* __restrict__ rank,
                          const int* __restrict__ cntO,
                          const int* __restrict__ cntI,
                          int4* __restrict__ cslot) {
  int e = blockIdx.x * 256 + threadIdx.x;
  if (e < NE) {
    int s = src[e], d = dst[e];
    int slot = rowptr[d] + rank[e];
    float nm = rsqrtf((float)max(cntO[s], 1) * (float)max(cntI[d], 1));
    int4 q;
    q.x = e;
    q.y = s;
    q.z = __float_as_int(nm);
    q.w = 0;
    cslot[slot] = q;
  }
}

// ====== GIANT kernel: degree count (interleaved) + node/edge MLPs ==========
// MLP blocks process TWO 128-row tiles; BOTH tiles' global loads are issued
// up front into registers (T14 async-stage) so tile1's HBM latency hides
// under tile0's MFMA chain. Count blocks capture rank[e].
template <int FIN>
__device__ __forceinline__ void stage_regs(const float* __restrict__ xin,
                                           int r0w, int nR,
                                           float4* __restrict__ rv) {
  const int l = threadIdx.x & 63;
  int row = l >> 1, half = l & 1;
  int r = r0w + row;
  bool ok = r < nR;
  constexpr int NQ = FIN / 8;  // float4s/thread: 32->4, 16->2, 8->1
  int cq = half * (FIN / 2);
#pragma unroll
  for (int q = 0; q < NQ; ++q) {
    rv[q] = make_float4(0.f, 0.f, 0.f, 0.f);
    if (ok) rv[q] = *(const float4*)(xin + (size_t)r * FIN + cq + q * 4);
  }
}

template <int FIN, bool NODE>
__device__ __forceinline__ void mlp_from_regs(
    ushort (*__restrict__ A)[72], const float4* __restrict__ rv,
    const ushort* __restrict__ pk, int pkb, const float* __restrict__ B0,
    const float* __restrict__ B1, const float* __restrict__ B2,
    ushort* __restrict__ msg, ushort* __restrict__ hnb, int r0w, int nR,
    int ebase) {
  const int l = threadIdx.x & 63;
  const int g = l >> 4, c = l & 15;

  // ---- convert staged regs -> LDS A (bf16), row = l>>1, half = l&1 ----
  {
    int row = l >> 1, half = l & 1;
    constexpr int NQ = FIN / 8;
    int cq = half * (FIN / 2);
#pragma unroll
    for (int q = 0; q < NQ; ++q)
      *(ushort4*)&A[row][cq + q * 4] = make_ushort4(
          f2bf(rv[q].x), f2bf(rv[q].y), f2bf(rv[q].z), f2bf(rv[q].w));
  }
  asm volatile("s_waitcnt lgkmcnt(0)" ::: "memory");  // same-wave LDS RAW

  f32x4 acc[2][4];
  // ===== L1 (K padded to 32) =====
#pragma unroll
  for (int nt = 0; nt < 4; ++nt) {
    float b = B0[nt * 16 + c];
    acc[0][nt] = f32x4{b, b, b, b};
    acc[1][nt] = acc[0][nt];
  }
  {
    bf16x8 a0 = {}, a1 = {};
    if (g * 8 < FIN) {
      a0 = *(const bf16x8*)&A[c][g * 8];
      a1 = *(const bf16x8*)&A[16 + c][g * 8];
    }
#pragma unroll
    for (int nt = 0; nt < 4; ++nt) {
      bf16x8 bb = *(const bf16x8*)&pk[(size_t)(pkb + nt) * 512 + l * 8];
      acc[0][nt] = __builtin_amdgcn_mfma_f32_16x16x32_bf16(a0, bb, acc[0][nt], 0, 0, 0);
      acc[1][nt] = __builtin_amdgcn_mfma_f32_16x16x32_bf16(a1, bb, acc[1][nt], 0, 0, 0);
    }
  }
#pragma unroll
  for (int t = 0; t < 2; ++t)
#pragma unroll
    for (int nt = 0; nt < 4; ++nt)
#pragma unroll
      for (int r = 0; r < 4; ++r)
        A[t * 16 + g * 4 + r][nt * 16 + c] = f2bf(fmaxf(acc[t][nt][r], 0.f));
  asm volatile("s_waitcnt lgkmcnt(0)" ::: "memory");

  // ===== L2 (K=64) =====
#pragma unroll
  for (int nt = 0; nt < 4; ++nt) {
    float b = B1[nt * 16 + c];
    acc[0][nt] = f32x4{b, b, b, b};
    acc[1][nt] = acc[0][nt];
  }
  {
    bf16x8 x00 = *(const bf16x8*)&A[c][g * 8];
    bf16x8 x01 = *(const bf16x8*)&A[c][32 + g * 8];
    bf16x8 x10 = *(const bf16x8*)&A[16 + c][g * 8];
    bf16x8 x11 = *(const bf16x8*)&A[16 + c][32 + g * 8];
#pragma unroll
    for (int nt = 0; nt < 4; ++nt) {
      bf16x8 bb0 = *(const bf16x8*)&pk[(size_t)(pkb + 4 + nt * 2) * 512 + l * 8];
      bf16x8 bb1 = *(const bf16x8*)&pk[(size_t)(pkb + 5 + nt * 2) * 512 + l * 8];
      acc[0][nt] = __builtin_amdgcn_mfma_f32_16x16x32_bf16(x00, bb0, acc[0][nt], 0, 0, 0);
      acc[0][nt] = __builtin_amdgcn_mfma_f32_16x16x32_bf16(x01, bb1, acc[0][nt], 0, 0, 0);
      acc[1][nt] = __builtin_amdgcn_mfma_f32_16x16x32_bf16(x10, bb0, acc[1][nt], 0, 0, 0);
      acc[1][nt] = __builtin_amdgcn_mfma_f32_16x16x32_bf16(x11, bb1, acc[1][nt], 0, 0, 0);
    }
  }
#pragma unroll
  for (int t = 0; t < 2; ++t)
#pragma unroll
    for (int nt = 0; nt < 4; ++nt)
#pragma unroll
      for (int r = 0; r < 4; ++r)
        A[t * 16 + g * 4 + r][nt * 16 + c] = f2bf(fmaxf(acc[t][nt][r], 0.f));
  asm volatile("s_waitcnt lgkmcnt(0)" ::: "memory");

  // ===== L3 (K=64, no relu) =====
#pragma unroll
  for (int nt = 0; nt < 4; ++nt) {
    float b = B2[nt * 16 + c];
    acc[0][nt] = f32x4{b, b, b, b};
    acc[1][nt] = acc[0][nt];
  }
  {
    bf16x8 x00 = *(const bf16x8*)&A[c][g * 8];
    bf16x8 x01 = *(const bf16x8*)&A[c][32 + g * 8];
    bf16x8 x10 = *(const bf16x8*)&A[16 + c][g * 8];
    bf16x8 x11 = *(const bf16x8*)&A[16 + c][32 + g * 8];
#pragma unroll
    for (int nt = 0; nt < 4; ++nt) {
      bf16x8 bb0 = *(const bf16x8*)&pk[(size_t)(pkb + 12 + nt * 2) * 512 + l * 8];
      bf16x8 bb1 = *(const bf16x8*)&pk[(size_t)(pkb + 13 + nt * 2) * 512 + l * 8];
      acc[0][nt] = __builtin_amdgcn_mfma_f32_16x16x32_bf16(x00, bb0, acc[0][nt], 0, 0, 0);
      acc[0][nt] = __builtin_amdgcn_mfma_f32_16x16x32_bf16(x01, bb1, acc[0][nt], 0, 0, 0);
      acc[1][nt] = __builtin_amdgcn_mfma_f32_16x16x32_bf16(x10, bb0, acc[1][nt], 0, 0, 0);
      acc[1][nt] = __builtin_amdgcn_mfma_f32_16x16x32_bf16(x11, bb1, acc[1][nt], 0, 0, 0);
    }
  }

  // ===== epilogue: park bf16 in A row-major, coalesced u16x8 row stores ====
  {
    ushort* outb = NODE ? hnb : msg;
    int obase = NODE ? r0w : (ebase + r0w);
#pragma unroll
    for (int t = 0; t < 2; ++t)
#pragma unroll
      for (int nt = 0; nt < 4; ++nt)
#pragma unroll
        for (int r = 0; r < 4; ++r)
          A[t * 16 + g * 4 + r][nt * 16 + c] = f2bf(acc[t][nt][r]);
    asm volatile("s_waitcnt lgkmcnt(0)" ::: "memory");
#pragma unroll
    for (int p = 0; p < 4; ++p) {
      int row = p * 8 + (l >> 3);
      int col8 = (l & 7) * 8;
      u16x8 v = *(const u16x8*)&A[row][col8];
      if (r0w + row < nR)
        *(u16x8*)(outb + (size_t)(obase + row) * DD + col8) = v;
    }
  }
}

// Two tiles per wave: both stages issued up front, tile1's loads complete
// during tile0's compute (compiler inserts the vmcnt wait at first use).
template <int FIN, bool NODE>
__device__ __forceinline__ void mlp_2tile(
    ushort (*__restrict__ A)[72], const float* __restrict__ xin,
    const ushort* __restrict__ pk, int pkb, const float* __restrict__ B0,
    const float* __restrict__ B1, const float* __restrict__ B2,
    ushort* __restrict__ msg, ushort* __restrict__ hnb, int base, int nR,
    int ebase) {
  float4 rv0[FIN / 8], rv1[FIN / 8];
  stage_regs<FIN>(xin, base, nR, rv0);
  stage_regs<FIN>(xin, base + 128, nR, rv1);
  mlp_from_regs<FIN, NODE>(A, rv0, pk, pkb, B0, B1, B2, msg, hnb, base, nR,
                           ebase);
  mlp_from_regs<FIN, NODE>(A, rv1, pk, pkb, B0, B1, B2, msg, hnb, base + 128,
                           nR, ebase);
}

__global__ __launch_bounds__(256, 6) void giant_k(
    const float* __restrict__ nf, const float* __restrict__ ef0,
    const float* __restrict__ ef1, const ushort* __restrict__ pk,
    const float* __restrict__ nb0, const float* __restrict__ nb1,
    const float* __restrict__ nb2, const float* __restrict__ b00,
    const float* __restrict__ b01, const float* __restrict__ b02,
    const float* __restrict__ b10, const float* __restrict__ b11,
    const float* __restrict__ b12, const int* __restrict__ src,
    const int* __restrict__ dst, int* __restrict__ cntO,
    int* __restrict__ cntI, int* __restrict__ rank,
    ushort* __restrict__ msg, ushort* __restrict__ hnb,
    int NBc4, int NBn, int NB0v, int NB1v) {
  __shared__ __align__(16) ushort act[4][32][72];
  int bid = blockIdx.x, tid = threadIdx.x, wid = tid >> 6;
  int cnum = bid / ILV;
  if (bid % ILV == ILV - 1) {
    if (cnum < NBc4) {
      int t4 = (cnum * 256 + tid) * 4;
      if (t4 < NE) {  // NE % 4 == 0
        int4 s4 = *(const int4*)(src + t4);
        int4 d4 = *(const int4*)(dst + t4);
        atomicAdd(cntO + s4.x, 1);
        atomicAdd(cntO + s4.y, 1);
        atomicAdd(cntO + s4.z, 1);
        atomicAdd(cntO + s4.w, 1);
        int4 r;
        r.x = atomicAdd(cntI + d4.x, 1);
        r.y = atomicAdd(cntI + d4.y, 1);
        r.z = atomicAdd(cntI + d4.z, 1);
        r.w = atomicAdd(cntI + d4.w, 1);
        *(int4*)(rank + t4) = r;
      }
    }
    return;
  }
  int mb = bid - cnum;  // mlp block index (count blocks removed)
  if (mb >= NBn + NB0v + NB1v) return;
  ushort (*A)[72] = act[wid];
  if (mb < NBn) {
    mlp_2tile<32, true>(A, nf, pk, 40, nb0, nb1, nb2, nullptr, hnb,
                        mb * 256 + wid * 32, N_NODES, 0);
  } else if (mb < NBn + NB0v) {
    mlp_2tile<16, false>(A, ef0, pk, 0, b00, b01, b02, msg, nullptr,
                         (mb - NBn) * 256 + wid * 32, NE0, 0);
  } else {
    mlp_2tile<8, false>(A, ef1, pk, 20, b10, b11, b12, msg, nullptr,
                        (mb - NBn - NB0v) * 256 + wid * 32, NE1, NE0);
  }
}

// ======================= wide streaming gather + conv1 =====================
// 16 CSR slots in flight per wave; packed int4 meta; bf16 msg + bf16 hn.
__global__ __launch_bounds__(256) void gather_conv1_k(
    const int* __restrict__ rowptr, const int* __restrict__ deg,
    const int4* __restrict__ cslot, const ushort* __restrict__ msgb,
    const ushort* __restrict__ hnb, const float* __restrict__ c1w,
    const float* __restrict__ c1b, const float* __restrict__ c2w,
    float* __restrict__ sbuf) {
  int w = threadIdx.x >> 6, l = threadIdx.x & 63;
  int g = l >> 4, c = l & 15;
  int n = blockIdx.x * 4 + w;
  if (n >= N_NODES) return;
  int r0 = rowptr[n], r1 = r0 + deg[n];
  float a0 = 0.f, a1 = 0.f, a2 = 0.f, a3 = 0.f, sn = 0.f;
  for (int j0 = r0; j0 < r1; j0 += 16) {
#pragma unroll
    for (int u = 0; u < 4; ++u) {
      int j = j0 + u * 4 + g;
      bool v = j < r1;
      int js = v ? j : r0;
      int4 q = cslot[js];
      int e = q.x, s = q.y;
      float nm = v ? __int_as_float(q.z) : 0.f;
      ushort4 m = *(const ushort4*)(msgb + (size_t)e * DD + c * 4);
      ushort4 h = *(const ushort4*)(hnb + (size_t)s * DD + c * 4);
      a0 = fmaf(nm, bf2f(m.x) + bf2f(h.x), a0);
      a1 = fmaf(nm, bf2f(m.y) + bf2f(h.y), a1);
      a2 = fmaf(nm, bf2f(m.z) + bf2f(h.z), a2);
      a3 = fmaf(nm, bf2f(m.w) + bf2f(h.w), a3);
      sn += nm;
    }
  }
  a0 += __shfl_xor(a0, 16); a0 += __shfl_xor(a0, 32);
  a1 += __shfl_xor(a1, 16); a1 += __shfl_xor(a1, 32);
  a2 += __shfl_xor(a2, 16); a2 += __shfl_xor(a2, 32);
  a3 += __shfl_xor(a3, 16); a3 += __shfl_xor(a3, 32);
  sn += __shfl_xor(sn, 16); sn += __shfl_xor(sn, 32);
  ushort4 hv = *(const ushort4*)(hnb + (size_t)n * DD + c * 4);
  a0 = fmaf(sn, bf2f(hv.x), a0);
  a1 = fmaf(sn, bf2f(hv.y), a1);
  a2 = fmaf(sn, bf2f(hv.z), a2);
  a3 = fmaf(sn, bf2f(hv.w), a3);
  __shared__ float Asm[4][64];
  if (g == 0) *(float4*)&Asm[w][c * 4] = make_float4(a0, a1, a2, a3);
  // wave-local LDS RAW (HW-proven pattern, rounds 3-15)
  float h = c1b[l];
#pragma unroll 8
  for (int k = 0; k < 64; ++k) h = fmaf(Asm[w][k], c1w[k * DD + l], h);
  h = fmaxf(h, 0.f);
  float v = h * c2w[l];
#pragma unroll
  for (int d = 32; d; d >>= 1) v += __shfl_xor(v, d);
  if (l == 0) sbuf[n] = v;
}

// conv2: 16 lanes per node, parallel loads, packed meta.
__global__ __launch_bounds__(256) void conv2_gather_k(
    const int* __restrict__ rowptr, const int* __restrict__ deg,
    const int4* __restrict__ cslot, const float* __restrict__ sbuf,
    const float* __restrict__ c2b, float* __restrict__ out) {
  int n = blockIdx.x * 16 + (threadIdx.x >> 4);
  int c = threadIdx.x & 15;
  if (n >= N_NODES) return;
  int r0 = rowptr[n], r1 = r0 + deg[n];
  float a = 0.f;
  for (int j = r0 + c; j < r1; j += 16) {
    int4 q = cslot[j];
    a = fmaf(__int_as_float(q.z), sbuf[q.y], a);
  }
  a += __shfl_xor(a, 1, 16);
  a += __shfl_xor(a, 2, 16);
  a += __shfl_xor(a, 4, 16);
  a += __shfl_xor(a, 8, 16);
  if (c == 0) out[n] = a + c2b[0];
}

// ---------------------------------------------------------------------------
extern "C" void kernel_launch(void* const* d_in, const int* in_sizes, int n_in,
                              void* d_out, int out_size, void* d_ws,
                              size_t ws_size, hipStream_t stream) {
  const float* nf   = (const float*)d_in[0];
  const float* ef0  = (const float*)d_in[1];
  const float* ef1  = (const float*)d_in[2];
  const float* n_w0 = (const float*)d_in[3];  const float* n_b0 = (const float*)d_in[4];
  const float* n_w1 = (const float*)d_in[5];  const float* n_b1 = (const float*)d_in[6];
  const float* n_w2 = (const float*)d_in[7];  const float* n_b2 = (const float*)d_in[8];
  const float* e0w0 = (const float*)d_in[9];  const float* e0b0 = (const float*)d_in[10];
  const float* e0w1 = (const float*)d_in[11]; const float* e0b1 = (const float*)d_in[12];
  const float* e0w2 = (const float*)d_in[13]; const float* e0b2 = (const float*)d_in[14];
  const float* e1w0 = (const float*)d_in[15]; const float* e1b0 = (const float*)d_in[16];
  const float* e1w1 = (const float*)d_in[17]; const float* e1b1 = (const float*)d_in[18];
  const float* e1w2 = (const float*)d_in[19]; const float* e1b2 = (const float*)d_in[20];
  const float* c1w  = (const float*)d_in[21]; const float* c1b  = (const float*)d_in[22];
  const float* c2w  = (const float*)d_in[23]; const float* c2b  = (const float*)d_in[24];
  const int* src = (const int*)d_in[25];
  const int* dst = (const int*)d_in[26];
  float* out = (float*)d_out;
  float* ws = (float*)d_ws;

  // ---- workspace layout (4B units) ----
  ushort* hnb    = (ushort*)ws;               // 3.2M ushorts = 1.6M floats
  float*  sbuf   = ws + 1600000;              // 50,000
  int*    rowptr = (int*)(ws + 1650000);      // 50,000
  int*    cntI   = (int*)(ws + 1700008);      // 50,000 (cntI,cntO,gbase zeroed)
  int*    cntO   = (int*)(ws + 1750008);      // 50,000
  int*    gbase  = (int*)(ws + 1800008);      // 8
  int*    rank   = (int*)(ws + 1810000);      // 800,000
  int4*   cslot  = (int4*)(ws + 2610000);     // 800,000 int4 (16B-aligned)
  ushort* msg    = (ushort*)(ws + 5810000);   // 51.2M ushorts = 25.6M floats
  ushort* pk     = (ushort*)(ws + 31410000);  // 30,720 ushorts
  // end ~31.43M floats = 126 MB

  const int NB   = (N_NODES + 255) / 256;   // 196
  const int NBn  = (N_NODES + 255) / 256;   // 196 (256 rows/block now)
  const int NB0  = (NE0 + 255) / 256;       // 1954
  const int NB1  = (NE1 + 255) / 256;       // 1172
  const int NBc  = (NE + 255) / 256;        // 3126
  const int NBc4 = (NE + 1023) / 1024;      // 782 (4 edges/thread)

  // giant grid: interleave count blocks 1-in-ILV; T such that both roles fit.
  const int NMLP = NBn + NB0 + NB1;  // 3322
  int T = NMLP + NBc4;               // 4104
  while (T / ILV < NBc4 || T - T / ILV < NMLP) ++T;  // -> ~4155

  hipMemsetAsync(cntI, 0, (size_t)100016 * sizeof(int), stream);
  pack_k<<<60, 64, 0, stream>>>(e0w0, e0w1, e0w2, e1w0, e1w1, e1w2, n_w0,
                                n_w1, n_w2, pk);
  giant_k<<<T, 256, 0, stream>>>(
      nf, ef0, ef1, pk, n_b0, n_b1, n_b2, e0b0, e0b1, e0b2, e1b0, e1b1, e1b2,
      src, dst, cntO, cntI, rank, msg, hnb, NBc4, NBn, NB0, NB1);
  scan_k<<<NB, 256, 0, stream>>>(cntI, rowptr, gbase);
  scatter_k<<<NBc, 256, 0, stream>>>(src, dst, rowptr, rank, cntO, cntI,
                                     cslot);
  gather_conv1_k<<<(N_NODES + 3) / 4, 256, 0, stream>>>(
      rowptr, cntI, cslot, msg, hnb, c1w, c1b, c2w, sbuf);
  conv2_gather_k<<<(N_NODES + 15) / 16, 256, 0, stream>>>(
      rowptr, cntI, cslot, sbuf, c2b, out);
}

// Round 17
// 190.711 us; speedup vs baseline: 2.3154x; 2.3154x over previous
//
#include <hip/hip_runtime.h>

#define N_NODES 50000
#define NE0 500000
#define NE1 300000
#define NE (NE0 + NE1)
#define DD 64
#define ILV 9  // every 9th block in giant_k is a degree-count block

typedef __bf16 bf16x8 __attribute__((ext_vector_type(8)));
typedef float f32x4 __attribute__((ext_vector_type(4)));
typedef unsigned short u16x8 __attribute__((ext_vector_type(8)));

__device__ __forceinline__ ushort f2bf(float x) {  // RNE via native cvt
  union { __bf16 h; ushort u; } v;
  v.h = (__bf16)x;
  return v.u;
}
__device__ __forceinline__ float bf2f(ushort u) {
  union { unsigned u; float f; } v;
  v.u = ((unsigned)u) << 16;
  return v.f;
}

// ==================== weight pack (B-frag order) ===========================
__global__ void pack_k(const float* __restrict__ w00, const float* __restrict__ w01,
                       const float* __restrict__ w02, const float* __restrict__ w10,
                       const float* __restrict__ w11, const float* __restrict__ w12,
                       const float* __restrict__ w20, const float* __restrict__ w21,
                       const float* __restrict__ w22, ushort* __restrict__ pk) {
  int f = blockIdx.x, l = threadIdx.x;  // 60 blocks x 64 threads
  int t = f / 20, fl = f % 20;
  int layer, nt, ks;
  if (fl < 4) { layer = 0; nt = fl; ks = 0; }
  else if (fl < 12) { layer = 1; nt = (fl - 4) >> 1; ks = (fl - 4) & 1; }
  else { layer = 2; nt = (fl - 12) >> 1; ks = (fl - 12) & 1; }
  const float* Wt[3][3] = {{w00, w01, w02}, {w10, w11, w12}, {w20, w21, w22}};
  const int K0[3] = {16, 8, 32};
  const float* W = Wt[t][layer];
  int K = (layer == 0) ? K0[t] : 64;
  int g = l >> 4, c = l & 15;
  ushort o[8];
#pragma unroll
  for (int e = 0; e < 8; ++e) {
    int k = ks * 32 + g * 8 + e, n = nt * 16 + c;
    o[e] = f2bf((k < K) ? W[k * DD + n] : 0.f);
  }
  ushort4* d4 = (ushort4*)&pk[(size_t)f * 512 + l * 8];
  d4[0] = make_ushort4(o[0], o[1], o[2], o[3]);
  d4[1] = make_ushort4(o[4], o[5], o[6], o[7]);
}

// ==================== order-free single-pass scan ==========================
__device__ __forceinline__ int block_scan_excl(int x, int tid, int* total) {
  int lane = tid & 63, w = tid >> 6;
  int incl = x;
#pragma unroll
  for (int d = 1; d < 64; d <<= 1) {
    int y = __shfl_up(incl, d);
    if (lane >= d) incl += y;
  }
  __shared__ int wsum[4];
  if (lane == 63) wsum[w] = incl;
  __syncthreads();
  int woff = 0;
  if (w > 0) woff = wsum[0];
  if (w > 1) woff += wsum[1];
  if (w > 2) woff += wsum[2];
  *total = wsum[0] + wsum[1] + wsum[2] + wsum[3];
  return woff + incl - x;
}

__global__ __launch_bounds__(256) void scan_k(const int* __restrict__ cnt,
                                              int* __restrict__ rowptr,
                                              int* __restrict__ gbase) {
  int i = blockIdx.x * 256 + threadIdx.x;
  int x = (i < N_NODES) ? cnt[i] : 0;
  int tot;
  int ex = block_scan_excl(x, threadIdx.x, &tot);
  __shared__ int base;
  if (threadIdx.x == 0) base = atomicAdd(gbase, tot);
  __syncthreads();
  if (i < N_NODES) rowptr[i] = base + ex;
}

// scatter: atomic-free. slot = rowptr[d] + rank[e]; one packed 16B store.
__global__ void scatter_k(const int* __restrict__ src, const int* __restrict__ dst,
                          const int* __restrict__ rowptr,
                          const int* __restrict__ rank,
                          const int* __restrict__ cntO,
                          const int* __restrict__ cntI,
                          int4* __restrict__ cslot) {
  int e = blockIdx.x * 256 + threadIdx.x;
  if (e < NE) {
    int s = src[e], d = dst[e];
    int slot = rowptr[d] + rank[e];
    float nm = rsqrtf((float)max(cntO[s], 1) * (float)max(cntI[d], 1));
    int4 q;
    q.x = e;
    q.y = s;
    q.z = __float_as_int(nm);
    q.w = 0;
    cslot[slot] = q;
  }
}

// ====== GIANT kernel: degree count (interleaved) + node/edge MLPs ==========
// Count blocks capture rank[e]; every ILV-th block counts (co-residency for
// the whole kernel). hn stored BF16 (halves gather's random-read volume).
template <int FIN, bool NODE>
__device__ __forceinline__ void mlp_body(
    ushort (*__restrict__ A)[72], const float* __restrict__ xin,
    const ushort* __restrict__ pk, int pkb, const float* __restrict__ B0,
    const float* __restrict__ B1, const float* __restrict__ B2,
    ushort* __restrict__ msg, ushort* __restrict__ hnb, int r0w, int nR,
    int ebase) {
  const int l = threadIdx.x & 63;
  const int g = l >> 4, c = l & 15;

  // ---- stage 32 input rows (bf16), coalesced: row = l>>1, half = l&1 ----
  {
    int row = l >> 1, half = l & 1;
    int r = r0w + row;
    bool ok = r < nR;
    if (FIN == 32) {
      int cq = half * 16;
#pragma unroll
      for (int q = 0; q < 4; ++q) {
        float4 v = make_float4(0.f, 0.f, 0.f, 0.f);
        if (ok) v = *(const float4*)(xin + (size_t)r * 32 + cq + q * 4);
        *(ushort4*)&A[row][cq + q * 4] =
            make_ushort4(f2bf(v.x), f2bf(v.y), f2bf(v.z), f2bf(v.w));
      }
    } else if (FIN == 16) {
      int cq = half * 8;
#pragma unroll
      for (int q = 0; q < 2; ++q) {
        float4 v = make_float4(0.f, 0.f, 0.f, 0.f);
        if (ok) v = *(const float4*)(xin + (size_t)r * 16 + cq + q * 4);
        *(ushort4*)&A[row][cq + q * 4] =
            make_ushort4(f2bf(v.x), f2bf(v.y), f2bf(v.z), f2bf(v.w));
      }
    } else {
      int cq = half * 4;
      float4 v = make_float4(0.f, 0.f, 0.f, 0.f);
      if (ok) v = *(const float4*)(xin + (size_t)r * 8 + cq);
      *(ushort4*)&A[row][cq] =
          make_ushort4(f2bf(v.x), f2bf(v.y), f2bf(v.z), f2bf(v.w));
    }
  }
  asm volatile("s_waitcnt lgkmcnt(0)" ::: "memory");  // same-wave LDS RAW

  f32x4 acc[2][4];
  // ===== L1 (K padded to 32) =====
#pragma unroll
  for (int nt = 0; nt < 4; ++nt) {
    float b = B0[nt * 16 + c];
    acc[0][nt] = f32x4{b, b, b, b};
    acc[1][nt] = acc[0][nt];
  }
  {
    bf16x8 a0 = {}, a1 = {};
    if (g * 8 < FIN) {
      a0 = *(const bf16x8*)&A[c][g * 8];
      a1 = *(const bf16x8*)&A[16 + c][g * 8];
    }
#pragma unroll
    for (int nt = 0; nt < 4; ++nt) {
      bf16x8 bb = *(const bf16x8*)&pk[(size_t)(pkb + nt) * 512 + l * 8];
      acc[0][nt] = __builtin_amdgcn_mfma_f32_16x16x32_bf16(a0, bb, acc[0][nt], 0, 0, 0);
      acc[1][nt] = __builtin_amdgcn_mfma_f32_16x16x32_bf16(a1, bb, acc[1][nt], 0, 0, 0);
    }
  }
#pragma unroll
  for (int t = 0; t < 2; ++t)
#pragma unroll
    for (int nt = 0; nt < 4; ++nt)
#pragma unroll
      for (int r = 0; r < 4; ++r)
        A[t * 16 + g * 4 + r][nt * 16 + c] = f2bf(fmaxf(acc[t][nt][r], 0.f));
  asm volatile("s_waitcnt lgkmcnt(0)" ::: "memory");

  // ===== L2 (K=64) =====
#pragma unroll
  for (int nt = 0; nt < 4; ++nt) {
    float b = B1[nt * 16 + c];
    acc[0][nt] = f32x4{b, b, b, b};
    acc[1][nt] = acc[0][nt];
  }
  {
    bf16x8 x00 = *(const bf16x8*)&A[c][g * 8];
    bf16x8 x01 = *(const bf16x8*)&A[c][32 + g * 8];
    bf16x8 x10 = *(const bf16x8*)&A[16 + c][g * 8];
    bf16x8 x11 = *(const bf16x8*)&A[16 + c][32 + g * 8];
#pragma unroll
    for (int nt = 0; nt < 4; ++nt) {
      bf16x8 bb0 = *(const bf16x8*)&pk[(size_t)(pkb + 4 + nt * 2) * 512 + l * 8];
      bf16x8 bb1 = *(const bf16x8*)&pk[(size_t)(pkb + 5 + nt * 2) * 512 + l * 8];
      acc[0][nt] = __builtin_amdgcn_mfma_f32_16x16x32_bf16(x00, bb0, acc[0][nt], 0, 0, 0);
      acc[0][nt] = __builtin_amdgcn_mfma_f32_16x16x32_bf16(x01, bb1, acc[0][nt], 0, 0, 0);
      acc[1][nt] = __builtin_amdgcn_mfma_f32_16x16x32_bf16(x10, bb0, acc[1][nt], 0, 0, 0);
      acc[1][nt] = __builtin_amdgcn_mfma_f32_16x16x32_bf16(x11, bb1, acc[1][nt], 0, 0, 0);
    }
  }
#pragma unroll
  for (int t = 0; t < 2; ++t)
#pragma unroll
    for (int nt = 0; nt < 4; ++nt)
#pragma unroll
      for (int r = 0; r < 4; ++r)
        A[t * 16 + g * 4 + r][nt * 16 + c] = f2bf(fmaxf(acc[t][nt][r], 0.f));
  asm volatile("s_waitcnt lgkmcnt(0)" ::: "memory");

  // ===== L3 (K=64, no relu) =====
#pragma unroll
  for (int nt = 0; nt < 4; ++nt) {
    float b = B2[nt * 16 + c];
    acc[0][nt] = f32x4{b, b, b, b};
    acc[1][nt] = acc[0][nt];
  }
  {
    bf16x8 x00 = *(const bf16x8*)&A[c][g * 8];
    bf16x8 x01 = *(const bf16x8*)&A[c][32 + g * 8];
    bf16x8 x10 = *(const bf16x8*)&A[16 + c][g * 8];
    bf16x8 x11 = *(const bf16x8*)&A[16 + c][32 + g * 8];
#pragma unroll
    for (int nt = 0; nt < 4; ++nt) {
      bf16x8 bb0 = *(const bf16x8*)&pk[(size_t)(pkb + 12 + nt * 2) * 512 + l * 8];
      bf16x8 bb1 = *(const bf16x8*)&pk[(size_t)(pkb + 13 + nt * 2) * 512 + l * 8];
      acc[0][nt] = __builtin_amdgcn_mfma_f32_16x16x32_bf16(x00, bb0, acc[0][nt], 0, 0, 0);
      acc[0][nt] = __builtin_amdgcn_mfma_f32_16x16x32_bf16(x01, bb1, acc[0][nt], 0, 0, 0);
      acc[1][nt] = __builtin_amdgcn_mfma_f32_16x16x32_bf16(x10, bb0, acc[1][nt], 0, 0, 0);
      acc[1][nt] = __builtin_amdgcn_mfma_f32_16x16x32_bf16(x11, bb1, acc[1][nt], 0, 0, 0);
    }
  }

  // ===== epilogue: park bf16 in A row-major, coalesced u16x8 row stores ====
  {
    ushort* outb = NODE ? hnb : msg;
    int obase = NODE ? r0w : (ebase + r0w);
#pragma unroll
    for (int t = 0; t < 2; ++t)
#pragma unroll
      for (int nt = 0; nt < 4; ++nt)
#pragma unroll
        for (int r = 0; r < 4; ++r)
          A[t * 16 + g * 4 + r][nt * 16 + c] = f2bf(acc[t][nt][r]);
    asm volatile("s_waitcnt lgkmcnt(0)" ::: "memory");
#pragma unroll
    for (int p = 0; p < 4; ++p) {
      int row = p * 8 + (l >> 3);
      int col8 = (l & 7) * 8;
      u16x8 v = *(const u16x8*)&A[row][col8];
      if (r0w + row < nR)
        *(u16x8*)(outb + (size_t)(obase + row) * DD + col8) = v;
    }
  }
}

__global__ __launch_bounds__(256, 8) void giant_k(
    const float* __restrict__ nf, const float* __restrict__ ef0,
    const float* __restrict__ ef1, const ushort* __restrict__ pk,
    const float* __restrict__ nb0, const float* __restrict__ nb1,
    const float* __restrict__ nb2, const float* __restrict__ b00,
    const float* __restrict__ b01, const float* __restrict__ b02,
    const float* __restrict__ b10, const float* __restrict__ b11,
    const float* __restrict__ b12, const int* __restrict__ src,
    const int* __restrict__ dst, int* __restrict__ cntO,
    int* __restrict__ cntI, int* __restrict__ rank,
    ushort* __restrict__ msg, ushort* __restrict__ hnb,
    int NBc4, int NBn, int NB0v, int NB1v) {
  __shared__ __align__(16) ushort act[4][32][72];
  int bid = blockIdx.x, tid = threadIdx.x, wid = tid >> 6;
  int cnum = bid / ILV;
  if (bid % ILV == ILV - 1) {
    if (cnum < NBc4) {
      int t4 = (cnum * 256 + tid) * 4;
      if (t4 < NE) {  // NE % 4 == 0
        int4 s4 = *(const int4*)(src + t4);
        int4 d4 = *(const int4*)(dst + t4);
        atomicAdd(cntO + s4.x, 1);
        atomicAdd(cntO + s4.y, 1);
        atomicAdd(cntO + s4.z, 1);
        atomicAdd(cntO + s4.w, 1);
        int4 r;
        r.x = atomicAdd(cntI + d4.x, 1);
        r.y = atomicAdd(cntI + d4.y, 1);
        r.z = atomicAdd(cntI + d4.z, 1);
        r.w = atomicAdd(cntI + d4.w, 1);
        *(int4*)(rank + t4) = r;
      }
    }
    return;
  }
  int mb = bid - cnum;  // mlp block index (count blocks removed)
  if (mb >= NBn + NB0v + NB1v) return;
  ushort (*A)[72] = act[wid];
  if (mb < NBn) {
    mlp_body<32, true>(A, nf, pk, 40, nb0, nb1, nb2, nullptr, hnb,
                       mb * 128 + wid * 32, N_NODES, 0);
  } else if (mb < NBn + NB0v) {
    mlp_body<16, false>(A, ef0, pk, 0, b00, b01, b02, msg, nullptr,
                        (mb - NBn) * 128 + wid * 32, NE0, 0);
  } else {
    mlp_body<8, false>(A, ef1, pk, 20, b10, b11, b12, msg, nullptr,
                       (mb - NBn - NB0v) * 128 + wid * 32, NE1, NE0);
  }
}

// ======================= wide streaming gather + conv1 =====================
// 16 CSR slots in flight per wave; packed int4 meta; bf16 msg + bf16 hn.
__global__ __launch_bounds__(256) void gather_conv1_k(
    const int* __restrict__ rowptr, const int* __restrict__ deg,
    const int4* __restrict__ cslot, const ushort* __restrict__ msgb,
    const ushort* __restrict__ hnb, const float* __restrict__ c1w,
    const float* __restrict__ c1b, const float* __restrict__ c2w,
    float* __restrict__ sbuf) {
  int w = threadIdx.x >> 6, l = threadIdx.x & 63;
  int g = l >> 4, c = l & 15;
  int n = blockIdx.x * 4 + w;
  if (n >= N_NODES) return;
  int r0 = rowptr[n], r1 = r0 + deg[n];
  float a0 = 0.f, a1 = 0.f, a2 = 0.f, a3 = 0.f, sn = 0.f;
  for (int j0 = r0; j0 < r1; j0 += 16) {
#pragma unroll
    for (int u = 0; u < 4; ++u) {
      int j = j0 + u * 4 + g;
      bool v = j < r1;
      int js = v ? j : r0;
      int4 q = cslot[js];
      int e = q.x, s = q.y;
      float nm = v ? __int_as_float(q.z) : 0.f;
      ushort4 m = *(const ushort4*)(msgb + (size_t)e * DD + c * 4);
      ushort4 h = *(const ushort4*)(hnb + (size_t)s * DD + c * 4);
      a0 = fmaf(nm, bf2f(m.x) + bf2f(h.x), a0);
      a1 = fmaf(nm, bf2f(m.y) + bf2f(h.y), a1);
      a2 = fmaf(nm, bf2f(m.z) + bf2f(h.z), a2);
      a3 = fmaf(nm, bf2f(m.w) + bf2f(h.w), a3);
      sn += nm;
    }
  }
  a0 += __shfl_xor(a0, 16); a0 += __shfl_xor(a0, 32);
  a1 += __shfl_xor(a1, 16); a1 += __shfl_xor(a1, 32);
  a2 += __shfl_xor(a2, 16); a2 += __shfl_xor(a2, 32);
  a3 += __shfl_xor(a3, 16); a3 += __shfl_xor(a3, 32);
  sn += __shfl_xor(sn, 16); sn += __shfl_xor(sn, 32);
  ushort4 hv = *(const ushort4*)(hnb + (size_t)n * DD + c * 4);
  a0 = fmaf(sn, bf2f(hv.x), a0);
  a1 = fmaf(sn, bf2f(hv.y), a1);
  a2 = fmaf(sn, bf2f(hv.z), a2);
  a3 = fmaf(sn, bf2f(hv.w), a3);
  __shared__ float Asm[4][64];
  if (g == 0) *(float4*)&Asm[w][c * 4] = make_float4(a0, a1, a2, a3);
  // wave-local LDS RAW (HW-proven pattern, rounds 3-14)
  float h = c1b[l];
#pragma unroll 8
  for (int k = 0; k < 64; ++k) h = fmaf(Asm[w][k], c1w[k * DD + l], h);
  h = fmaxf(h, 0.f);
  float v = h * c2w[l];
#pragma unroll
  for (int d = 32; d; d >>= 1) v += __shfl_xor(v, d);
  if (l == 0) sbuf[n] = v;
}

// conv2: 16 lanes per node, parallel loads, packed meta.
__global__ __launch_bounds__(256) void conv2_gather_k(
    const int* __restrict__ rowptr, const int* __restrict__ deg,
    const int4* __restrict__ cslot, const float* __restrict__ sbuf,
    const float* __restrict__ c2b, float* __restrict__ out) {
  int n = blockIdx.x * 16 + (threadIdx.x >> 4);
  int c = threadIdx.x & 15;
  if (n >= N_NODES) return;
  int r0 = rowptr[n], r1 = r0 + deg[n];
  float a = 0.f;
  for (int j = r0 + c; j < r1; j += 16) {
    int4 q = cslot[j];
    a = fmaf(__int_as_float(q.z), sbuf[q.y], a);
  }
  a += __shfl_xor(a, 1, 16);
  a += __shfl_xor(a, 2, 16);
  a += __shfl_xor(a, 4, 16);
  a += __shfl_xor(a, 8, 16);
  if (c == 0) out[n] = a + c2b[0];
}

// ---------------------------------------------------------------------------
extern "C" void kernel_launch(void* const* d_in, const int* in_sizes, int n_in,
                              void* d_out, int out_size, void* d_ws,
                              size_t ws_size, hipStream_t stream) {
  const float* nf   = (const float*)d_in[0];
  const float* ef0  = (const float*)d_in[1];
  const float* ef1  = (const float*)d_in[2];
  const float* n_w0 = (const float*)d_in[3];  const float* n_b0 = (const float*)d_in[4];
  const float* n_w1 = (const float*)d_in[5];  const float* n_b1 = (const float*)d_in[6];
  const float* n_w2 = (const float*)d_in[7];  const float* n_b2 = (const float*)d_in[8];
  const float* e0w0 = (const float*)d_in[9];  const float* e0b0 = (const float*)d_in[10];
  const float* e0w1 = (const float*)d_in[11]; const float* e0b1 = (const float*)d_in[12];
  const float* e0w2 = (const float*)d_in[13]; const float* e0b2 = (const float*)d_in[14];
  const float* e1w0 = (const float*)d_in[15]; const float* e1b0 = (const float*)d_in[16];
  const float* e1w1 = (const float*)d_in[17]; const float* e1b1 = (const float*)d_in[18];
  const float* e1w2 = (const float*)d_in[19]; const float* e1b2 = (const float*)d_in[20];
  const float* c1w  = (const float*)d_in[21]; const float* c1b  = (const float*)d_in[22];
  const float* c2w  = (const float*)d_in[23]; const float* c2b  = (const float*)d_in[24];
  const int* src = (const int*)d_in[25];
  const int* dst = (const int*)d_in[26];
  float* out = (float*)d_out;
  float* ws = (float*)d_ws;

  // ---- workspace layout (4B units) ----
  ushort* hnb    = (ushort*)ws;               // 3.2M ushorts = 1.6M floats
  float*  sbuf   = ws + 1600000;              // 50,000
  int*    rowptr = (int*)(ws + 1650000);      // 50,000
  int*    cntI   = (int*)(ws + 1700008);      // 50,000 (cntI,cntO,gbase zeroed)
  int*    cntO   = (int*)(ws + 1750008);      // 50,000
  int*    gbase  = (int*)(ws + 1800008);      // 8
  int*    rank   = (int*)(ws + 1810000);      // 800,000
  int4*   cslot  = (int4*)(ws + 2610000);     // 800,000 int4 (16B-aligned)
  ushort* msg    = (ushort*)(ws + 5810000);   // 51.2M ushorts = 25.6M floats
  ushort* pk     = (ushort*)(ws + 31410000);  // 30,720 ushorts
  // end ~31.43M floats = 126 MB

  const int NB   = (N_NODES + 255) / 256;   // 196
  const int NBn  = (N_NODES + 127) / 128;   // 391
  const int NB0  = (NE0 + 127) / 128;       // 3907
  const int NB1  = (NE1 + 127) / 128;       // 2344
  const int NBc  = (NE + 255) / 256;        // 3126
  const int NBc4 = (NE + 1023) / 1024;      // 782 (4 edges/thread)

  // giant grid: interleave count blocks 1-in-ILV; T such that both roles fit.
  const int NMLP = NBn + NB0 + NB1;  // 6642
  int T = NMLP + NBc4;               // 7424
  while (T / ILV < NBc4 || T - T / ILV < NMLP) ++T;  // -> 7475

  hipMemsetAsync(cntI, 0, (size_t)100016 * sizeof(int), stream);
  pack_k<<<60, 64, 0, stream>>>(e0w0, e0w1, e0w2, e1w0, e1w1, e1w2, n_w0,
                                n_w1, n_w2, pk);
  giant_k<<<T, 256, 0, stream>>>(
      nf, ef0, ef1, pk, n_b0, n_b1, n_b2, e0b0, e0b1, e0b2, e1b0, e1b1, e1b2,
      src, dst, cntO, cntI, rank, msg, hnb, NBc4, NBn, NB0, NB1);
  scan_k<<<NB, 256, 0, stream>>>(cntI, rowptr, gbase);
  scatter_k<<<NBc, 256, 0, stream>>>(src, dst, rowptr, rank, cntO, cntI,
                                     cslot);
  gather_conv1_k<<<(N_NODES + 3) / 4, 256, 0, stream>>>(
      rowptr, cntI, cslot, msg, hnb, c1w, c1b, c2w, sbuf);
  conv2_gather_k<<<(N_NODES + 15) / 16, 256, 0, stream>>>(
      rowptr, cntI, cslot, sbuf, c2b, out);
}